// Round 6
// baseline (31.946 us; speedup 1.0000x reference)
//
#include <hip/hip_runtime.h>
#include <math.h>

// ---------------------------------------------------------------------------
// Z_exp = Tr(M rho^x4), M = W^dag Z0 W = degree-4 poly in Bloch (x,y,z),
// 35 monomials. R5 showed barrier-separated 256-thread stages cost ~0.75us
// each at 1-block occupancy (21.6us precompute). Now: ONE fused kernel;
// wave 0 of every block computes the coefficients wave-synchronously
// (W rows in registers, __shfl row-gather, zero barriers), one
// __syncthreads, then all 512 threads evaluate 2 elements each.
// ---------------------------------------------------------------------------

struct cpx { float re, im; };

__device__ __forceinline__ cpx cmul(cpx a, cpx b) {
    return { a.re * b.re - a.im * b.im, a.re * b.im + a.im * b.re };
}

// ---- compile-time Pauli-string -> monomial grouping (data-independent) ----
struct MonoTab { unsigned char cnt[125]; unsigned char idx[125][24]; };

constexpr int mono_of(int p) {
    int a = 0, b = 0, c = 0;
    for (int k = 0; k < 4; ++k) {
        const int pk = (p >> (2 * k)) & 3;   // 0=I,1=X,2=Y,3=Z
        a += (pk == 1); b += (pk == 2); c += (pk == 3);
    }
    return (a * 5 + b) * 5 + c;
}
constexpr MonoTab build_tab() {
    MonoTab t{};
    for (int m = 0; m < 125; ++m) {
        t.cnt[m] = 0;
        for (int k = 0; k < 24; ++k) t.idx[m][k] = 0;
    }
    for (int p = 0; p < 256; ++p) {          // ascending p: same sum order as R5
        const int m = mono_of(p);
        t.idx[m][t.cnt[m]++] = (unsigned char)p;
    }
    return t;
}
__constant__ const MonoTab TAB = build_tab();

#define WAVE_SYNC asm volatile("s_waitcnt lgkmcnt(0)" ::: "memory")

__global__ __launch_bounds__(512) void fused_kernel(
    const float4* __restrict__ in, const float* __restrict__ w_U,
    const float* __restrict__ w_RXZX, const float* __restrict__ scale_p,
    const float* __restrict__ bias_p, float2* __restrict__ out, int B2)
{
    __shared__ cpx   Wb[16][16];     // final unitary (dumped from registers)
    __shared__ cpx   Mm[16][16];     // W^dag Z0 W
    __shared__ float cp[256];        // Pauli-basis coefficients
    __shared__ cpx   R[24][2][2];    // RXZX 2x2 gates
    __shared__ cpx   LM[12][4][4];   // fused 4x4 layer matrices
    __shared__ float ISc[6], ISs[6];
    __shared__ float cf[125];        // monomial coefficients

    const int tid = threadIdx.x;
    const int idx = blockIdx.x * 512 + tid;

    // prefetch this thread's 2 batch elements (vmcnt waited at use, after coef)
    float4 f = make_float4(0.f, 0.f, 0.f, 0.f);
    if (idx < B2) f = in[idx];

    if (tid < 64) {
        const int L = tid;

        // ---- A1: 2x2 RXZX gates + iSWAP params ----
        if (L < 24) {
            const float ta = w_RXZX[L * 3 + 0];
            const float tb = w_RXZX[L * 3 + 1];
            const float tc = w_RXZX[L * 3 + 2];
            float sa, ca, sb, cb, sc, cc;
            sincosf(0.5f * ta, &sa, &ca);
            sincosf(0.5f * tb, &sb, &cb);
            sincosf(0.5f * tc, &sc, &cc);
            const cpx e0 = { cb, -sb };
            const cpx e1 = { cb,  sb };
            const cpx T00 = { e0.re * cc, e0.im * cc };
            const cpx T01 = { -e0.im * (-sc), e0.re * (-sc) };
            const cpx T10 = { -e1.im * (-sc), e1.re * (-sc) };
            const cpx T11 = { e1.re * cc, e1.im * cc };
            const cpx g00 = { ca * T00.re + sa * T10.im, ca * T00.im - sa * T10.re };
            const cpx g01 = { ca * T01.re + sa * T11.im, ca * T01.im - sa * T11.re };
            const cpx g10 = { sa * T00.im + ca * T10.re, -sa * T00.re + ca * T10.im };
            const cpx g11 = { sa * T01.im + ca * T11.re, -sa * T01.re + ca * T11.im };
            R[L][0][0] = g00; R[L][0][1] = g01;
            R[L][1][0] = g10; R[L][1][1] = g11;
        } else if (L < 30) {
            const int l = L - 24;
            const float t = w_U[l];
            ISc[l] = cosf(t);
            ISs[l] = sinf(t);
        }
        WAVE_SYNC;

        // ---- A2: fused 4x4 layer matrices, 3 entries per lane (192 total) ----
        #pragma unroll
        for (int kk = 0; kk < 3; ++kk) {
            const int e2 = L + 64 * kk;
            const int m = e2 >> 4, e = e2 & 15, u = e >> 2, w = e & 3;
            const int l = m >> 1;
            const unsigned long long PAIR = 0xD89C8DC98DC9ULL;
            const int code = (int)((PAIR >> (8 * l)) & 0xFF);
            const int sh = (m & 1) ? 4 : 0;
            const int qa  = (code >> sh) & 3;
            const int qb2 = (code >> (sh + 2)) & 3;
            const int ra = l * 4 + qa, rb = l * 4 + qb2;
            cpx res;
            if (m & 1) {
                res = cmul(R[ra][u >> 1][w >> 1], R[rb][u & 1][w & 1]);
            } else {
                if (w == 0)      res = cmul(R[ra][u >> 1][0], R[rb][u & 1][0]);
                else if (w == 3) res = cmul(R[ra][u >> 1][1], R[rb][u & 1][1]);
                else {
                    const cpx k1 = cmul(R[ra][u >> 1][0], R[rb][u & 1][1]);
                    const cpx k2 = cmul(R[ra][u >> 1][1], R[rb][u & 1][0]);
                    const cpx tc = (w == 1) ? k1 : k2;  // * c
                    const cpx ts = (w == 1) ? k2 : k1;  // * i s
                    const float c = ISc[l], s = ISs[l];
                    res.re = c * tc.re - s * ts.im;
                    res.im = c * tc.im + s * ts.re;
                }
            }
            LM[m][u][w] = res;
        }
        WAVE_SYNC;

        // ---- Sweep: W in registers; lane = (row i, col-quad jq) ----
        const int i = L >> 2, jq = L & 3;
        float wre[4], wim[4];
        #pragma unroll
        for (int c = 0; c < 4; ++c) {
            wre[c] = (i == 4 * jq + c) ? 1.f : 0.f;
            wim[c] = 0.f;
        }
        constexpr int QA[12] = {1,0, 1,0, 1,0, 1,0, 0,1, 0,1};
        constexpr int QB[12] = {2,3, 3,2, 2,3, 3,2, 3,2, 2,3};
        #pragma unroll
        for (int s = 0; s < 12; ++s) {
            const int qa = QA[s], qb2 = QB[s];
            const int wa = 8 >> qa, wb = 8 >> qb2;
            const int u = (((i >> (3 - qa)) & 1) << 1) | ((i >> (3 - qb2)) & 1);
            const int base = i & ~(wa | wb);
            const cpx g0 = LM[s][u][0], g1 = LM[s][u][1];
            const cpx g2 = LM[s][u][2], g3 = LM[s][u][3];
            const int rr[4] = { base, base | wb, base | wa, base | wa | wb };
            float xr[4][4], xi[4][4];
            #pragma unroll
            for (int t = 0; t < 4; ++t) {
                const int src = rr[t] * 4 + jq;
                #pragma unroll
                for (int c = 0; c < 4; ++c) {
                    xr[t][c] = __shfl(wre[c], src);
                    xi[t][c] = __shfl(wim[c], src);
                }
            }
            #pragma unroll
            for (int c = 0; c < 4; ++c) {
                const float nre =
                    g0.re * xr[0][c] - g0.im * xi[0][c] + g1.re * xr[1][c] - g1.im * xi[1][c]
                  + g2.re * xr[2][c] - g2.im * xi[2][c] + g3.re * xr[3][c] - g3.im * xi[3][c];
                const float nim =
                    g0.re * xi[0][c] + g0.im * xr[0][c] + g1.re * xi[1][c] + g1.im * xr[1][c]
                  + g2.re * xi[2][c] + g2.im * xr[2][c] + g3.re * xi[3][c] + g3.im * xr[3][c];
                wre[c] = nre;
                wim[c] = nim;
            }
        }
        // dump final W to LDS
        #pragma unroll
        for (int c = 0; c < 4; ++c) Wb[i][4 * jq + c] = { wre[c], wim[c] };
        WAVE_SYNC;

        // ---- M[a][b] = sum_k zk conj(W[k][a]) W[k][b]; lane: a=L>>2, 4 b's ----
        {
            const int a = L >> 2, bq = L & 3;
            float mre[4] = {0.f, 0.f, 0.f, 0.f}, mim[4] = {0.f, 0.f, 0.f, 0.f};
            #pragma unroll
            for (int k = 0; k < 16; ++k) {
                const float zk = (k < 8) ? 1.f : -1.f;
                const cpx wa_ = Wb[k][a];
                #pragma unroll
                for (int c = 0; c < 4; ++c) {
                    const cpx wb_ = Wb[k][4 * bq + c];
                    mre[c] += zk * (wa_.re * wb_.re + wa_.im * wb_.im);
                    mim[c] += zk * (wa_.re * wb_.im - wa_.im * wb_.re);
                }
            }
            #pragma unroll
            for (int c = 0; c < 4; ++c) Mm[a][4 * bq + c] = { mre[c], mim[c] };
        }
        WAVE_SYNC;

        // ---- Pauli traces: 4 p's per lane ----
        #pragma unroll
        for (int kk = 0; kk < 4; ++kk) {
            const int p = L + 64 * kk;
            float accre = 0.f;
            #pragma unroll
            for (int col = 0; col < 16; ++col) {
                int row = 0;
                cpx val = {1.f, 0.f};
                #pragma unroll
                for (int k = 0; k < 4; ++k) {
                    const int pk = (p >> (6 - 2 * k)) & 3;
                    const int b = (col >> (3 - k)) & 1;
                    int rb = b;
                    if (pk == 1) {
                        rb = b ^ 1;
                    } else if (pk == 2) {
                        rb = b ^ 1;
                        cpx fc = {0.f, b ? -1.f : 1.f};
                        val = cmul(val, fc);
                    } else if (pk == 3) {
                        if (b) { val.re = -val.re; val.im = -val.im; }
                    }
                    row |= rb << (3 - k);
                }
                const cpx mv = Mm[col][row];
                accre += mv.re * val.re - mv.im * val.im;
            }
            cp[p] = accre * (1.f / 16.f);
        }
        WAVE_SYNC;

        // ---- collapse via compile-time table: 2 monomials per lane ----
        #pragma unroll
        for (int kk = 0; kk < 2; ++kk) {
            const int t = L + 64 * kk;
            if (t < 125) {
                const int cnt = TAB.cnt[t];
                float s = 0.f;
                #pragma unroll
                for (int k = 0; k < 24; ++k) {
                    const float v = cp[TAB.idx[t][k]];   // padded idx=0, masked below
                    s += (k < cnt) ? v : 0.f;
                }
                cf[t] = s;
            }
        }
    }
    __syncthreads();

    // ---- eval: 2 elements per thread from LDS coefficients ----
    if (idx >= B2) return;
    const float scale = scale_p[0], bias = bias_p[0];

    float2 res;
    #pragma unroll
    for (int e = 0; e < 2; ++e) {
        const float f0 = e ? f.z : f.x;
        const float f1 = e ? f.w : f.y;
        float s0, c0, s1, c1;
        sincosf(f0, &s0, &c0);
        sincosf(f1, &s1, &c1);
        const float x = s1 * c0, y = s1 * s0, z = c1;

        float xp[5], yp[5], zp[5];
        xp[0] = yp[0] = zp[0] = 1.f;
        #pragma unroll
        for (int k = 1; k < 5; ++k) {
            xp[k] = xp[k - 1] * x;
            yp[k] = yp[k - 1] * y;
            zp[k] = zp[k - 1] * z;
        }

        float Z = 0.f;
        #pragma unroll
        for (int a = 0; a <= 4; ++a)
            #pragma unroll
            for (int b = 0; b <= 4 - a; ++b)
                #pragma unroll
                for (int c = 0; c <= 4 - a - b; ++c)
                    Z = fmaf(cf[(a * 5 + b) * 5 + c], xp[a] * yp[b] * zp[c], Z);

        const float noise = 0.04472135954999579f * (Z * Z - 1.f) * 0.25f;
        const float v = scale * (Z + noise) + bias;
        if (e) res.y = v; else res.x = v;
    }
    out[idx] = res;
}

extern "C" void kernel_launch(void* const* d_in, const int* in_sizes, int n_in,
                              void* d_out, int out_size, void* d_ws, size_t ws_size,
                              hipStream_t stream) {
    const float* inputs  = (const float*)d_in[0];   // [B,2] f32
    const float* w_U     = (const float*)d_in[1];   // [6]
    const float* w_RXZX  = (const float*)d_in[2];   // [6,4,3]
    const float* scale_p = (const float*)d_in[3];   // [1]
    const float* bias_p  = (const float*)d_in[4];   // [1]
    float* out = (float*)d_out;

    const int B  = in_sizes[0] / 2;
    const int B2 = B / 2;                           // 2 elements per thread

    fused_kernel<<<(B2 + 511) / 512, 512, 0, stream>>>(
        (const float4*)inputs, w_U, w_RXZX, scale_p, bias_p, (float2*)out, B2);
}

// Round 7
// 30.080 us; speedup vs baseline: 1.0620x; 1.0620x over previous
//
#include <hip/hip_runtime.h>
#include <math.h>

// ---------------------------------------------------------------------------
// Z_exp = Tr(M rho^x4), M = W^dag Z0 W = degree-4 poly in Bloch (x,y,z),
// 35 monomials; eval is a per-element polynomial.
// R5: barrier phases cost ~0.75us each at 1-block/CU -> minimize phase count.
// R6 lesson: single-wave shuffle chain is WORSE (no TLP to hide ds latency).
// Now: 8 multi-wave phases: R gates -> 16x16 layer mats L[6] -> tree matmul
// {L1L0, L3L2, L5L4} -> D -> W -> M -> Pauli traces -> collapse; then fused
// eval (512 thr x 2 elems) reads cf from LDS. One dispatch.
// ---------------------------------------------------------------------------

struct cpx { float re, im; };

__device__ __forceinline__ cpx cmul(cpx a, cpx b) {
    return { a.re * b.re - a.im * b.im, a.re * b.im + a.im * b.re };
}

// ---- compile-time Pauli-string -> monomial grouping (data-independent) ----
struct MonoTab { unsigned char cnt[125]; unsigned char idx[125][24]; };

constexpr int mono_of(int p) {
    int a = 0, b = 0, c = 0;
    for (int k = 0; k < 4; ++k) {
        const int pk = (p >> (2 * k)) & 3;   // 0=I,1=X,2=Y,3=Z
        a += (pk == 1); b += (pk == 2); c += (pk == 3);
    }
    return (a * 5 + b) * 5 + c;
}
constexpr MonoTab build_tab() {
    MonoTab t{};
    for (int m = 0; m < 125; ++m) {
        t.cnt[m] = 0;
        for (int k = 0; k < 24; ++k) t.idx[m][k] = 0;
    }
    for (int p = 0; p < 256; ++p) {          // ascending p: fixed sum order
        const int m = mono_of(p);
        t.idx[m][t.cnt[m]++] = (unsigned char)p;
    }
    return t;
}
__constant__ const MonoTab TAB = build_tab();

__global__ __launch_bounds__(512) void fused_kernel(
    const float4* __restrict__ in, const float* __restrict__ w_U,
    const float* __restrict__ w_RXZX, const float* __restrict__ scale_p,
    const float* __restrict__ bias_p, float2* __restrict__ out, int B2)
{
    __shared__ cpx   R[24][2][2];    // RXZX 2x2 gates
    __shared__ float ISc[6], ISs[6]; // iSWAP cos/sin
    __shared__ cpx   L[6][16][16];   // full 16x16 layer matrices
    __shared__ cpx   Am[16][16], Bm[16][16], Cm[16][16];  // L1L0, L3L2, L5L4
    __shared__ cpx   Dm[16][16];     // Bm*Am
    __shared__ cpx   Wf[16][16];     // Cm*Dm  (final unitary)
    __shared__ cpx   Mm[16][16];     // W^dag Z0 W
    __shared__ float cp[256];        // Pauli-basis coefficients
    __shared__ float cf[125];        // monomial coefficients

    const int tid = threadIdx.x;
    const int idx = blockIdx.x * 512 + tid;

    // prefetch this thread's 2 batch elements (hidden under the chain)
    float4 f = make_float4(0.f, 0.f, 0.f, 0.f);
    if (idx < B2) f = in[idx];

    // ---- Phase 1: 2x2 RXZX gates + iSWAP params (24+6 threads) ----
    if (tid < 24) {
        const float ta = w_RXZX[tid * 3 + 0];
        const float tb = w_RXZX[tid * 3 + 1];
        const float tc = w_RXZX[tid * 3 + 2];
        float sa, ca, sb, cb, sc, cc;
        sincosf(0.5f * ta, &sa, &ca);
        sincosf(0.5f * tb, &sb, &cb);
        sincosf(0.5f * tc, &sc, &cc);
        // RX(t)=[[c,-is],[-is,c]], RZ(t)=diag(c-is, c+is); g = RX(a)RZ(b)RX(c)
        const cpx e0 = { cb, -sb };
        const cpx e1 = { cb,  sb };
        const cpx T00 = { e0.re * cc, e0.im * cc };
        const cpx T01 = { -e0.im * (-sc), e0.re * (-sc) };
        const cpx T10 = { -e1.im * (-sc), e1.re * (-sc) };
        const cpx T11 = { e1.re * cc, e1.im * cc };
        const cpx g00 = { ca * T00.re + sa * T10.im, ca * T00.im - sa * T10.re };
        const cpx g01 = { ca * T01.re + sa * T11.im, ca * T01.im - sa * T11.re };
        const cpx g10 = { sa * T00.im + ca * T10.re, -sa * T00.re + ca * T10.im };
        const cpx g11 = { sa * T01.im + ca * T11.re, -sa * T01.re + ca * T11.im };
        R[tid][0][0] = g00; R[tid][0][1] = g01;
        R[tid][1][0] = g10; R[tid][1][1] = g11;
    } else if (tid < 30) {
        const int l = tid - 24;
        const float t = w_U[l];
        ISc[l] = cosf(t);
        ISs[l] = sinf(t);
    }
    __syncthreads();

    const int i = (tid >> 4) & 15, j = tid & 15;   // (row,col) for 256-thread phases

    // ---- Phase 2: build L[l][i][j] = GA[uA(i)][uA(j)] * GB[uB(i)][uB(j)]
    //      GA = (R_qa (x) R_qb) * iSWAP(t_l)   on the iSWAP pair
    //      GB =  R_qr (x) R_qs                 on the complement pair
    // PAIR byte per layer: qa | qb<<2 | qr<<4 | qs<<6 ;
    // PAIRS=[(1,2),(1,3),(1,2),(1,3),(0,3),(0,2)].
    if (tid < 256) {
        #pragma unroll
        for (int l = 0; l < 6; ++l) {
            const unsigned long long PAIR = 0xD89C8DC98DC9ULL;
            const int code = (int)((PAIR >> (8 * l)) & 0xFF);
            const int qa = code & 3, qb = (code >> 2) & 3;
            const int qr = (code >> 4) & 3, qs = (code >> 6) & 3;
            const int uAi = (((i >> (3 - qa)) & 1) << 1) | ((i >> (3 - qb)) & 1);
            const int uAj = (((j >> (3 - qa)) & 1) << 1) | ((j >> (3 - qb)) & 1);
            const int uBi = (((i >> (3 - qr)) & 1) << 1) | ((i >> (3 - qs)) & 1);
            const int uBj = (((j >> (3 - qr)) & 1) << 1) | ((j >> (3 - qs)) & 1);
            const int ra = l * 4 + qa, rb = l * 4 + qb;
            cpx ga;
            if (uAj == 0)      ga = cmul(R[ra][uAi >> 1][0], R[rb][uAi & 1][0]);
            else if (uAj == 3) ga = cmul(R[ra][uAi >> 1][1], R[rb][uAi & 1][1]);
            else {
                const cpx k1 = cmul(R[ra][uAi >> 1][0], R[rb][uAi & 1][1]);
                const cpx k2 = cmul(R[ra][uAi >> 1][1], R[rb][uAi & 1][0]);
                const cpx tc = (uAj == 1) ? k1 : k2;   // * cos
                const cpx ts = (uAj == 1) ? k2 : k1;   // * i sin
                const float c = ISc[l], s = ISs[l];
                ga.re = c * tc.re - s * ts.im;
                ga.im = c * tc.im + s * ts.re;
            }
            const cpx gb = cmul(R[l * 4 + qr][uBi >> 1][uBj >> 1],
                                R[l * 4 + qs][uBi & 1][uBj & 1]);
            L[l][i][j] = cmul(ga, gb);
        }
    }
    __syncthreads();

    // ---- Phase 3: tree level 1 — A=L1*L0, B=L3*L2, C=L5*L4 (3 dots/thread)
    if (tid < 256) {
        cpx a = {0.f, 0.f}, b = {0.f, 0.f}, c = {0.f, 0.f};
        #pragma unroll
        for (int k = 0; k < 16; ++k) {
            a.re += L[1][i][k].re * L[0][k][j].re - L[1][i][k].im * L[0][k][j].im;
            a.im += L[1][i][k].re * L[0][k][j].im + L[1][i][k].im * L[0][k][j].re;
            b.re += L[3][i][k].re * L[2][k][j].re - L[3][i][k].im * L[2][k][j].im;
            b.im += L[3][i][k].re * L[2][k][j].im + L[3][i][k].im * L[2][k][j].re;
            c.re += L[5][i][k].re * L[4][k][j].re - L[5][i][k].im * L[4][k][j].im;
            c.im += L[5][i][k].re * L[4][k][j].im + L[5][i][k].im * L[4][k][j].re;
        }
        Am[i][j] = a; Bm[i][j] = b; Cm[i][j] = c;
    }
    __syncthreads();

    // ---- Phase 4: D = B*A ----
    if (tid < 256) {
        cpx d = {0.f, 0.f};
        #pragma unroll
        for (int k = 0; k < 16; ++k) {
            d.re += Bm[i][k].re * Am[k][j].re - Bm[i][k].im * Am[k][j].im;
            d.im += Bm[i][k].re * Am[k][j].im + Bm[i][k].im * Am[k][j].re;
        }
        Dm[i][j] = d;
    }
    __syncthreads();

    // ---- Phase 5: W = C*D ----
    if (tid < 256) {
        cpx w = {0.f, 0.f};
        #pragma unroll
        for (int k = 0; k < 16; ++k) {
            w.re += Cm[i][k].re * Dm[k][j].re - Cm[i][k].im * Dm[k][j].im;
            w.im += Cm[i][k].re * Dm[k][j].im + Cm[i][k].im * Dm[k][j].re;
        }
        Wf[i][j] = w;
    }
    __syncthreads();

    // ---- Phase 6: M[i][j] = sum_k zk conj(W[k][i]) W[k][j], zk=+1 (k<8) else -1
    if (tid < 256) {
        cpx m = {0.f, 0.f};
        #pragma unroll
        for (int k = 0; k < 16; ++k) {
            const float zk = (k < 8) ? 1.f : -1.f;
            const cpx a = Wf[k][i];
            const cpx b = Wf[k][j];
            m.re += zk * (a.re * b.re + a.im * b.im);   // conj(a)*b
            m.im += zk * (a.re * b.im - a.im * b.re);
        }
        Mm[i][j] = m;
    }
    __syncthreads();

    // ---- Phase 7: Pauli traces cp[p] = Tr(M*P_p)/16, p = tid ----
    if (tid < 256) {
        const int p = tid;
        float accre = 0.f;
        #pragma unroll
        for (int col = 0; col < 16; ++col) {
            int row = 0;
            cpx val = {1.f, 0.f};
            #pragma unroll
            for (int k = 0; k < 4; ++k) {
                const int pk = (p >> (6 - 2 * k)) & 3;
                const int b = (col >> (3 - k)) & 1;
                int rb = b;
                if (pk == 1) {
                    rb = b ^ 1;
                } else if (pk == 2) {
                    rb = b ^ 1;
                    cpx fc = {0.f, b ? -1.f : 1.f};
                    val = cmul(val, fc);
                } else if (pk == 3) {
                    if (b) { val.re = -val.re; val.im = -val.im; }
                }
                row |= rb << (3 - k);
            }
            const cpx mv = Mm[col][row];
            accre += mv.re * val.re - mv.im * val.im;
        }
        cp[p] = accre * (1.f / 16.f);
    }
    __syncthreads();

    // ---- Phase 8: collapse via compile-time table (125 threads) ----
    if (tid < 125) {
        const int cnt = TAB.cnt[tid];
        float s = 0.f;
        #pragma unroll
        for (int k = 0; k < 24; ++k) {
            const float v = cp[TAB.idx[tid][k]];
            s += (k < cnt) ? v : 0.f;
        }
        cf[tid] = s;
    }
    __syncthreads();

    // ---- eval: 2 elements per thread from LDS coefficients ----
    if (idx >= B2) return;
    const float scale = scale_p[0], bias = bias_p[0];

    float2 res;
    #pragma unroll
    for (int e = 0; e < 2; ++e) {
        const float f0 = e ? f.z : f.x;
        const float f1 = e ? f.w : f.y;
        float s0, c0, s1, c1;
        sincosf(f0, &s0, &c0);
        sincosf(f1, &s1, &c1);
        const float x = s1 * c0, y = s1 * s0, z = c1;

        float xp[5], yp[5], zp[5];
        xp[0] = yp[0] = zp[0] = 1.f;
        #pragma unroll
        for (int k = 1; k < 5; ++k) {
            xp[k] = xp[k - 1] * x;
            yp[k] = yp[k - 1] * y;
            zp[k] = zp[k - 1] * z;
        }

        float Z = 0.f;
        #pragma unroll
        for (int a = 0; a <= 4; ++a)
            #pragma unroll
            for (int b = 0; b <= 4 - a; ++b)
                #pragma unroll
                for (int c = 0; c <= 4 - a - b; ++c)
                    Z = fmaf(cf[(a * 5 + b) * 5 + c], xp[a] * yp[b] * zp[c], Z);

        const float noise = 0.04472135954999579f * (Z * Z - 1.f) * 0.25f;
        const float v = scale * (Z + noise) + bias;
        if (e) res.y = v; else res.x = v;
    }
    out[idx] = res;
}

extern "C" void kernel_launch(void* const* d_in, const int* in_sizes, int n_in,
                              void* d_out, int out_size, void* d_ws, size_t ws_size,
                              hipStream_t stream) {
    const float* inputs  = (const float*)d_in[0];   // [B,2] f32
    const float* w_U     = (const float*)d_in[1];   // [6]
    const float* w_RXZX  = (const float*)d_in[2];   // [6,4,3]
    const float* scale_p = (const float*)d_in[3];   // [1]
    const float* bias_p  = (const float*)d_in[4];   // [1]
    float* out = (float*)d_out;

    const int B  = in_sizes[0] / 2;
    const int B2 = B / 2;                           // 2 elements per thread

    fused_kernel<<<(B2 + 511) / 512, 512, 0, stream>>>(
        (const float4*)inputs, w_U, w_RXZX, scale_p, bias_p, (float2*)out, B2);
}

// Round 8
// 23.987 us; speedup vs baseline: 1.3318x; 1.2540x over previous
//
#include <hip/hip_runtime.h>
#include <math.h>

// ---------------------------------------------------------------------------
// Z_exp = Tr(M rho^x4) = degree-4 poly in Bloch (x,y,z), 35 monomials.
// R5-R7 showed chain cost (~21-26us) is INVARIANT to phase count/structure
// -> hypothesis: cold-I$ straight-line-code fetch + low 1-block utilization.
// R8: chain code COMPACTED (loops, no unrolling; all arrays in LDS so runtime
// indexing is legal), run redundantly on 256 blocks (spreads code fetch,
// raises utilization). Eval kernel = proven R5 version (unchanged).
// ---------------------------------------------------------------------------

struct cpx { float re, im; };

__device__ __forceinline__ cpx cmul(cpx a, cpx b) {
    return { a.re * b.re - a.im * b.im, a.re * b.im + a.im * b.re };
}

// ---- compile-time Pauli-string -> monomial grouping (data-independent) ----
struct MonoTab { unsigned char cnt[125]; unsigned char idx[125][24]; };

constexpr int mono_of(int p) {
    int a = 0, b = 0, c = 0;
    for (int k = 0; k < 4; ++k) {
        const int pk = (p >> (2 * k)) & 3;   // 0=I,1=X,2=Y,3=Z
        a += (pk == 1); b += (pk == 2); c += (pk == 3);
    }
    return (a * 5 + b) * 5 + c;
}
constexpr MonoTab build_tab() {
    MonoTab t{};
    for (int m = 0; m < 125; ++m) {
        t.cnt[m] = 0;
        for (int k = 0; k < 24; ++k) t.idx[m][k] = 0;
    }
    for (int p = 0; p < 256; ++p) {          // ascending p: fixed sum order
        const int m = mono_of(p);
        t.idx[m][t.cnt[m]++] = (unsigned char)p;
    }
    return t;
}
__constant__ const MonoTab TAB = build_tab();

// ---------------------------------------------------------------------------
// Kernel 1: coefficient chain. COMPACT CODE (no unrolling). 256 blocks all
// compute the same result; identical redundant stores are benign.
// ---------------------------------------------------------------------------
__global__ __launch_bounds__(256) void coef_kernel(
    const float* __restrict__ w_U, const float* __restrict__ w_RXZX,
    float* __restrict__ coef /* 125 floats */)
{
    __shared__ cpx   R[24][2][2];    // RXZX 2x2 gates
    __shared__ float ISc[6], ISs[6]; // iSWAP cos/sin
    __shared__ cpx   L[6][16][16];   // 16x16 layer matrices
    __shared__ cpx   P1[3][16][16];  // tree level 1: L1L0, L3L2, L5L4
    __shared__ cpx   Dm[16][16];     // P1[1]*P1[0]
    __shared__ cpx   Wf[16][16];     // P1[2]*Dm
    __shared__ cpx   Mm[16][16];     // W^dag Z0 W
    __shared__ float cp[256];        // Pauli-basis coefficients

    const int tid = threadIdx.x;
    const int i = tid >> 4, j = tid & 15;

    // ---- Phase 1: 2x2 RXZX gates + iSWAP params ----
    if (tid < 24) {
        const float ta = w_RXZX[tid * 3 + 0];
        const float tb = w_RXZX[tid * 3 + 1];
        const float tc = w_RXZX[tid * 3 + 2];
        float sa, ca, sb, cb, sc, cc;
        sincosf(0.5f * ta, &sa, &ca);
        sincosf(0.5f * tb, &sb, &cb);
        sincosf(0.5f * tc, &sc, &cc);
        // RX(t)=[[c,-is],[-is,c]], RZ(t)=diag(c-is,c+is); g = RX(a)RZ(b)RX(c)
        const cpx e0 = { cb, -sb };
        const cpx e1 = { cb,  sb };
        const cpx T00 = { e0.re * cc, e0.im * cc };
        const cpx T01 = { -e0.im * (-sc), e0.re * (-sc) };
        const cpx T10 = { -e1.im * (-sc), e1.re * (-sc) };
        const cpx T11 = { e1.re * cc, e1.im * cc };
        R[tid][0][0] = { ca * T00.re + sa * T10.im, ca * T00.im - sa * T10.re };
        R[tid][0][1] = { ca * T01.re + sa * T11.im, ca * T01.im - sa * T11.re };
        R[tid][1][0] = { sa * T00.im + ca * T10.re, -sa * T00.re + ca * T10.im };
        R[tid][1][1] = { sa * T01.im + ca * T11.re, -sa * T01.re + ca * T11.im };
    } else if (tid < 30) {
        const int l = tid - 24;
        float s, c;
        sincosf(w_U[l], &s, &c);
        ISc[l] = c;
        ISs[l] = s;
    }
    __syncthreads();

    // ---- Phase 2: L[l] = (GA on iSWAP pair) x (GB on complement pair) ----
    // PAIR byte per layer l: qa | qb<<2 | qr<<4 | qs<<6,
    // PAIRS=[(1,2),(1,3),(1,2),(1,3),(0,3),(0,2)]
    for (int l = 0; l < 6; ++l) {
        const int code = (int)((0xD89C8DC98DC9ULL >> (8 * l)) & 0xFF);
        const int qa = code & 3, qb = (code >> 2) & 3;
        const int qr = (code >> 4) & 3, qs = (code >> 6) & 3;
        const int uAi = (((i >> (3 - qa)) & 1) << 1) | ((i >> (3 - qb)) & 1);
        const int uAj = (((j >> (3 - qa)) & 1) << 1) | ((j >> (3 - qb)) & 1);
        const int uBi = (((i >> (3 - qr)) & 1) << 1) | ((i >> (3 - qs)) & 1);
        const int uBj = (((j >> (3 - qr)) & 1) << 1) | ((j >> (3 - qs)) & 1);
        const int ra = l * 4 + qa, rb = l * 4 + qb;
        cpx ga;
        if (uAj == 0)      ga = cmul(R[ra][uAi >> 1][0], R[rb][uAi & 1][0]);
        else if (uAj == 3) ga = cmul(R[ra][uAi >> 1][1], R[rb][uAi & 1][1]);
        else {
            const cpx k1 = cmul(R[ra][uAi >> 1][0], R[rb][uAi & 1][1]);
            const cpx k2 = cmul(R[ra][uAi >> 1][1], R[rb][uAi & 1][0]);
            const cpx tc = (uAj == 1) ? k1 : k2;   // * cos
            const cpx ts = (uAj == 1) ? k2 : k1;   // * i sin
            const float c = ISc[l], s = ISs[l];
            ga.re = c * tc.re - s * ts.im;
            ga.im = c * tc.im + s * ts.re;
        }
        const cpx gb = cmul(R[l * 4 + qr][uBi >> 1][uBj >> 1],
                            R[l * 4 + qs][uBi & 1][uBj & 1]);
        L[l][i][j] = cmul(ga, gb);
    }
    __syncthreads();

    // ---- Phase 3: tree level 1 — P1[m] = L[2m+1]*L[2m] ----
    for (int m = 0; m < 3; ++m) {
        cpx acc = {0.f, 0.f};
        for (int k = 0; k < 16; ++k) {
            const cpx a = L[2 * m + 1][i][k];
            const cpx b = L[2 * m][k][j];
            acc.re += a.re * b.re - a.im * b.im;
            acc.im += a.re * b.im + a.im * b.re;
        }
        P1[m][i][j] = acc;
    }
    __syncthreads();

    // ---- Phase 4: D = P1[1]*P1[0] ----
    {
        cpx acc = {0.f, 0.f};
        for (int k = 0; k < 16; ++k) {
            const cpx a = P1[1][i][k];
            const cpx b = P1[0][k][j];
            acc.re += a.re * b.re - a.im * b.im;
            acc.im += a.re * b.im + a.im * b.re;
        }
        Dm[i][j] = acc;
    }
    __syncthreads();

    // ---- Phase 5: W = P1[2]*D ----
    {
        cpx acc = {0.f, 0.f};
        for (int k = 0; k < 16; ++k) {
            const cpx a = P1[2][i][k];
            const cpx b = Dm[k][j];
            acc.re += a.re * b.re - a.im * b.im;
            acc.im += a.re * b.im + a.im * b.re;
        }
        Wf[i][j] = acc;
    }
    __syncthreads();

    // ---- Phase 6: M[i][j] = sum_k zk conj(W[k][i]) W[k][j] ----
    {
        cpx acc = {0.f, 0.f};
        for (int k = 0; k < 16; ++k) {
            const float zk = (k < 8) ? 1.f : -1.f;
            const cpx a = Wf[k][i];
            const cpx b = Wf[k][j];
            acc.re += zk * (a.re * b.re + a.im * b.im);   // conj(a)*b
            acc.im += zk * (a.re * b.im - a.im * b.re);
        }
        Mm[i][j] = acc;
    }
    __syncthreads();

    // ---- Phase 7: Pauli traces cp[p] = Tr(M*P_p)/16, p = tid ----
    {
        const int p = tid;
        float accre = 0.f;
        for (int col = 0; col < 16; ++col) {
            int row = 0;
            cpx val = {1.f, 0.f};
            for (int k = 0; k < 4; ++k) {
                const int pk = (p >> (6 - 2 * k)) & 3;
                const int b = (col >> (3 - k)) & 1;
                int rb = b;
                if (pk == 1) {
                    rb = b ^ 1;
                } else if (pk == 2) {
                    rb = b ^ 1;
                    const cpx f = {0.f, b ? -1.f : 1.f};
                    val = cmul(val, f);
                } else if (pk == 3) {
                    if (b) { val.re = -val.re; val.im = -val.im; }
                }
                row |= rb << (3 - k);
            }
            const cpx mv = Mm[col][row];
            accre += mv.re * val.re - mv.im * val.im;
        }
        cp[p] = accre * (1.f / 16.f);
    }
    __syncthreads();

    // ---- Phase 8: collapse via compile-time table (125 threads) ----
    if (tid < 125) {
        const int cnt = TAB.cnt[tid];
        float s = 0.f;
        for (int k = 0; k < cnt; ++k)          // ascending: deterministic
            s += cp[TAB.idx[tid][k]];
        coef[tid] = s;                          // identical across blocks
    }
}

// ---------------------------------------------------------------------------
// Kernel 2: eval (unchanged from R5 — measured ~6.3us incl. overhead)
// ---------------------------------------------------------------------------
__global__ __launch_bounds__(256) void eval_poly(
    const float4* __restrict__ in, const float* __restrict__ coef,
    const float* __restrict__ scale_p, const float* __restrict__ bias_p,
    float2* __restrict__ out, int B2)
{
    const int idx = blockIdx.x * blockDim.x + threadIdx.x;
    if (idx >= B2) return;

    const float4 f = in[idx];            // two elements: (f.x,f.y), (f.z,f.w)
    const float scale = scale_p[0], bias = bias_p[0];

    float2 res;
    #pragma unroll
    for (int e = 0; e < 2; ++e) {
        const float f0 = e ? f.z : f.x;
        const float f1 = e ? f.w : f.y;
        float s0, c0, s1, c1;
        sincosf(f0, &s0, &c0);
        sincosf(f1, &s1, &c1);
        const float x = s1 * c0, y = s1 * s0, z = c1;

        float xp[5], yp[5], zp[5];
        xp[0] = yp[0] = zp[0] = 1.f;
        #pragma unroll
        for (int k = 1; k < 5; ++k) {
            xp[k] = xp[k - 1] * x;
            yp[k] = yp[k - 1] * y;
            zp[k] = zp[k - 1] * z;
        }

        float Z = 0.f;
        #pragma unroll
        for (int a = 0; a <= 4; ++a)
            #pragma unroll
            for (int b = 0; b <= 4 - a; ++b)
                #pragma unroll
                for (int c = 0; c <= 4 - a - b; ++c)
                    Z = fmaf(coef[(a * 5 + b) * 5 + c], xp[a] * yp[b] * zp[c], Z);

        const float noise = 0.04472135954999579f * (Z * Z - 1.f) * 0.25f;
        const float v = scale * (Z + noise) + bias;
        if (e) res.y = v; else res.x = v;
    }
    out[idx] = res;
}

extern "C" void kernel_launch(void* const* d_in, const int* in_sizes, int n_in,
                              void* d_out, int out_size, void* d_ws, size_t ws_size,
                              hipStream_t stream) {
    const float* inputs  = (const float*)d_in[0];   // [B,2] f32
    const float* w_U     = (const float*)d_in[1];   // [6]
    const float* w_RXZX  = (const float*)d_in[2];   // [6,4,3]
    const float* scale_p = (const float*)d_in[3];   // [1]
    const float* bias_p  = (const float*)d_in[4];   // [1]
    float* out  = (float*)d_out;
    float* coef = (float*)d_ws;                     // 125 floats scratch

    const int B  = in_sizes[0] / 2;
    const int B2 = B / 2;                           // 2 elements per thread

    // 256 redundant blocks: spreads cold code-fetch across CUs, raises
    // utilization; all write identical coef values (deterministic).
    coef_kernel<<<256, 256, 0, stream>>>(w_U, w_RXZX, coef);
    eval_poly<<<(B2 + 255) / 256, 256, 0, stream>>>(
        (const float4*)inputs, coef, scale_p, bias_p, (float2*)out, B2);
}